// Round 13
// baseline (271.797 us; speedup 1.0000x reference)
//
#include <hip/hip_runtime.h>
#include <hip/hip_bf16.h>

#define NN   4096
#define HID  128
#define INFE 64
#define KE   160   // edge slots/row: Binomial(4096,0.02) max ~122 across 4096 rows
#define RPB  4

typedef unsigned short u16;
typedef unsigned int   u32;

__device__ __forceinline__ float bflo(u32 w){ return __uint_as_float(w << 16); }
__device__ __forceinline__ float bfhi(u32 w){ return __uint_as_float(w & 0xffff0000u); }
__device__ __forceinline__ u16 f2b(float f) { __hip_bfloat16 h = __float2bfloat16(f); return *(u16*)&h; }

// ---- h0 = x @ W_in + b_in ; writes fp32 h and bf16 mirror ----
__global__ __launch_bounds__(128) void k_h0(
    const float* __restrict__ x, const float* __restrict__ Win, const float* __restrict__ bin,
    float* __restrict__ hdst, u16* __restrict__ bdst)
{
    __shared__ float xl[INFE];
    const int r = blockIdx.x;
    const int d = threadIdx.x;
    if (d < INFE) xl[d] = x[(size_t)r*INFE + d];
    __syncthreads();
    float acc = bin[d];
    #pragma unroll 8
    for (int k = 0; k < INFE; ++k)
        acc = fmaf(xl[k], Win[k*HID + d], acc);
    hdst[(size_t)r*HID + d] = acc;
    bdst[(size_t)r*HID + d] = f2b(acc);
}

// ---- phase 1: pure adj stream -> compacted (col, a) per row; 4 rows/block ----
__global__ __launch_bounds__(256) void k_compact(
    const float* __restrict__ adj, int2* __restrict__ cols, int* __restrict__ nnzp)
{
    __shared__ int wtot[RPB][4];
    const int r0   = blockIdx.x * RPB;
    const int t    = threadIdx.x;
    const int w    = t >> 6;
    const int lane = t & 63;
    // 16 upfront coalesced float4 loads (256 B outstanding per thread)
    float4 a[RPB][4];
    #pragma unroll
    for (int rr = 0; rr < RPB; ++rr) {
        const float4* arow = (const float4*)(adj + (size_t)(r0+rr)*NN);
        #pragma unroll
        for (int q = 0; q < 4; ++q) a[rr][q] = arow[t + 256*q];
    }
    int cnt[RPB], incl[RPB];
    #pragma unroll
    for (int rr = 0; rr < RPB; ++rr) {
        int c = 0;
        #pragma unroll
        for (int q = 0; q < 4; ++q)
            c += (a[rr][q].x != 0.f) + (a[rr][q].y != 0.f) + (a[rr][q].z != 0.f) + (a[rr][q].w != 0.f);
        cnt[rr] = c; incl[rr] = c;
    }
    #pragma unroll
    for (int off = 1; off < 64; off <<= 1) {   // 4 interleaved scans
        int v0 = __shfl_up(incl[0], off);
        int v1 = __shfl_up(incl[1], off);
        int v2 = __shfl_up(incl[2], off);
        int v3 = __shfl_up(incl[3], off);
        if (lane >= off) { incl[0]+=v0; incl[1]+=v1; incl[2]+=v2; incl[3]+=v3; }
    }
    if (lane == 63) {
        #pragma unroll
        for (int rr = 0; rr < RPB; ++rr) wtot[rr][w] = incl[rr];
    }
    __syncthreads();
    #pragma unroll
    for (int rr = 0; rr < RPB; ++rr) {
        int wbase = 0;
        #pragma unroll
        for (int i = 0; i < 4; ++i) if (i < w) wbase += wtot[rr][i];
        const int total = wtot[rr][0] + wtot[rr][1] + wtot[rr][2] + wtot[rr][3];
        int slot = wbase + (incl[rr] - cnt[rr]);
        int2* crow = cols + (size_t)(r0+rr)*KE;
        #pragma unroll
        for (int q = 0; q < 4; ++q) {
            float v[4] = {a[rr][q].x, a[rr][q].y, a[rr][q].z, a[rr][q].w};
            #pragma unroll
            for (int u = 0; u < 4; ++u) {
                if (v[u] != 0.f) {
                    if (slot < KE)
                        crow[slot] = make_int2(4*(t + 256*q) + u, __float_as_int(v[u]));
                    ++slot;
                }
            }
        }
        const int n  = total < KE ? total : KE;
        const int np = (n + 15) / 16 * 16;                 // pad to x16
        for (int i = n + t; i < np; i += 256)
            crow[i] = make_int2(0, 0);
        if (t == 0) nnzp[r0+rr] = np;
    }
}

// ---- phase 2: one thread per edge slot; fully independent dist+math ----
__global__ __launch_bounds__(256) void k_weight(
    const int2* __restrict__ cols, const int* __restrict__ nnzp,
    const float* __restrict__ dist, float4* __restrict__ edges)
{
    const int tid = blockIdx.x*256 + threadIdx.x;          // NN*KE threads
    const int r   = tid / KE;
    const int i   = tid - r*KE;
    if (i >= nnzp[r]) return;
    int2 ca = cols[(size_t)r*KE + i];
    int   c = ca.x;
    float a = __int_as_float(ca.y);                        // 0 for pad slots
    float d  = fmaxf(dist[(size_t)r*NN + c], 1e-6f);
    float dw1 = a * __expf(-d * (1.0f/3.0f));
    float tt = 3.5f / d, t2 = tt*tt, t6 = t2*t2*t2;
    float dw2 = a * 0.04f * (t6*t6 - t6);                  // 0.1 * 4*eps*(sr12-sr6)
    edges[(size_t)r*KE + i] = make_float4(__int_as_float(c), dw1, dw2, 0.f);
}

// ---- fused step: 4 rows/block, wave=row, bf16 gathers, 16 edges/iter ----
__global__ __launch_bounds__(256) void k_fstep(
    const float4* __restrict__ edges, const int* __restrict__ nnzp,
    const float* __restrict__ h, const u16* __restrict__ hb,
    const float* __restrict__ Wu1, const float* __restrict__ bu1,
    const float* __restrict__ Wu2, const float* __restrict__ bu2,
    const float* __restrict__ gam, const float* __restrict__ bet,
    float* __restrict__ hout, u16* __restrict__ bout)
{
    __shared__ __align__(16) float4 eds[RPB][KE];   // 10 KB staged edge lists
    __shared__ int npl[RPB];
    __shared__ __align__(16) float hs[RPB][HID];
    __shared__ __align__(16) float ms[RPB][HID];
    __shared__ __align__(16) float h1s[RPB][HID];
    __shared__ float hn[RPB][HID];
    const int t    = threadIdx.x;
    const int w    = t >> 6;        // wave id = local row
    const int lane = t & 63;
    const int g    = lane >> 5;     // 32-lane half: edge parity
    const int j    = lane & 31;     // owns dims 4j..4j+3
    const int r0   = blockIdx.x * RPB;
    const int r    = r0 + w;

    if (t < RPB) npl[t] = nnzp[r0 + t];
    const float4 hi4 = *(const float4*)(h + (size_t)r*HID + 4*j);
    if (g == 0) *(float4*)&hs[w][4*j] = hi4;
    __syncthreads();
    #pragma unroll
    for (int rr = 0; rr < RPB; ++rr) {
        const float4* er = edges + (size_t)(r0+rr)*KE;
        for (int i = t; i < npl[rr]; i += 256) eds[rr][i] = er[i];
    }
    __syncthreads();

    // ---- message phase: 16 edges/iter, 8 in flight per 32-lane half ----
    const int np = npl[w];
    float4 macc = make_float4(0.f, 0.f, 0.f, 0.f);
    for (int e0 = 0; e0 < np; e0 += 16) {
        float4 ed[8]; uint2 hj16[8]; float p[8];
        #pragma unroll
        for (int q = 0; q < 8; ++q) ed[q] = eds[w][e0 + g + 2*q];
        #pragma unroll
        for (int q = 0; q < 8; ++q) {
            int c = __float_as_int(ed[q].x);
            hj16[q] = *(const uint2*)(hb + (size_t)c*HID + 4*j);   // 8 outstanding 8B gathers
        }
        float4 hjf[8];
        #pragma unroll
        for (int q = 0; q < 8; ++q) {
            hjf[q].x = bflo(hj16[q].x); hjf[q].y = bfhi(hj16[q].x);
            hjf[q].z = bflo(hj16[q].y); hjf[q].w = bfhi(hj16[q].y);
            p[q] = hi4.x*hjf[q].x;
            p[q] = fmaf(hi4.y, hjf[q].y, p[q]);
            p[q] = fmaf(hi4.z, hjf[q].z, p[q]);
            p[q] = fmaf(hi4.w, hjf[q].w, p[q]);
        }
        #pragma unroll
        for (int mask = 1; mask <= 16; mask <<= 1) {   // 8 independent chains
            #pragma unroll
            for (int q = 0; q < 8; ++q) p[q] += __shfl_xor(p[q], mask);
        }
        #pragma unroll
        for (int q = 0; q < 8; ++q) {
            float wq = fmaf(ed[q].y, fmaxf(p[q], 0.f), ed[q].z);
            macc.x = fmaf(wq, hjf[q].x, macc.x);
            macc.y = fmaf(wq, hjf[q].y, macc.y);
            macc.z = fmaf(wq, hjf[q].z, macc.z);
            macc.w = fmaf(wq, hjf[q].w, macc.w);
        }
    }
    macc.x += __shfl_xor(macc.x, 32);   // combine the two halves' edge subsets
    macc.y += __shfl_xor(macc.y, 32);
    macc.z += __shfl_xor(macc.z, 32);
    macc.w += __shfl_xor(macc.w, 32);
    if (g == 0) *(float4*)&ms[w][4*j] = macc;
    __syncthreads();

    // ---- MLP phase A: h1 = relu([h,m] @ Wu1 + b1); weights shared across 2 rows
    {
        const int half = t >> 7;
        const int d    = t & 127;
        const int ra = 2*half, rb = ra + 1;
        float bb = bu1[d];
        float a0 = bb, a1 = bb;
        for (int k = 0; k < HID; k += 4) {
            float w0 = Wu1[(k+0)*HID + d], w1 = Wu1[(k+1)*HID + d];
            float w2 = Wu1[(k+2)*HID + d], w3 = Wu1[(k+3)*HID + d];
            float4 caa = *(const float4*)&hs[ra][k];
            float4 cbb = *(const float4*)&hs[rb][k];
            a0 = fmaf(caa.x,w0,a0); a0 = fmaf(caa.y,w1,a0); a0 = fmaf(caa.z,w2,a0); a0 = fmaf(caa.w,w3,a0);
            a1 = fmaf(cbb.x,w0,a1); a1 = fmaf(cbb.y,w1,a1); a1 = fmaf(cbb.z,w2,a1); a1 = fmaf(cbb.w,w3,a1);
        }
        for (int k = 0; k < HID; k += 4) {
            float w0 = Wu1[(HID+k+0)*HID + d], w1 = Wu1[(HID+k+1)*HID + d];
            float w2 = Wu1[(HID+k+2)*HID + d], w3 = Wu1[(HID+k+3)*HID + d];
            float4 caa = *(const float4*)&ms[ra][k];
            float4 cbb = *(const float4*)&ms[rb][k];
            a0 = fmaf(caa.x,w0,a0); a0 = fmaf(caa.y,w1,a0); a0 = fmaf(caa.z,w2,a0); a0 = fmaf(caa.w,w3,a0);
            a1 = fmaf(cbb.x,w0,a1); a1 = fmaf(cbb.y,w1,a1); a1 = fmaf(cbb.z,w2,a1); a1 = fmaf(cbb.w,w3,a1);
        }
        h1s[ra][d] = fmaxf(a0, 0.f);
        h1s[rb][d] = fmaxf(a1, 0.f);
    }
    __syncthreads();
    // ---- MLP phase B: hn = h + (h1 @ Wu2 + b2)
    {
        const int half = t >> 7;
        const int d    = t & 127;
        const int ra = 2*half, rb = ra + 1;
        float bb = bu2[d];
        float b0 = bb, b1 = bb;
        for (int k = 0; k < HID; k += 4) {
            float w0 = Wu2[(k+0)*HID + d], w1 = Wu2[(k+1)*HID + d];
            float w2 = Wu2[(k+2)*HID + d], w3 = Wu2[(k+3)*HID + d];
            float4 caa = *(const float4*)&h1s[ra][k];
            float4 cbb = *(const float4*)&h1s[rb][k];
            b0 = fmaf(caa.x,w0,b0); b0 = fmaf(caa.y,w1,b0); b0 = fmaf(caa.z,w2,b0); b0 = fmaf(caa.w,w3,b0);
            b1 = fmaf(cbb.x,w0,b1); b1 = fmaf(cbb.y,w1,b1); b1 = fmaf(cbb.z,w2,b1); b1 = fmaf(cbb.w,w3,b1);
        }
        hn[ra][d] = hs[ra][d] + b0;
        hn[rb][d] = hs[rb][d] + b1;
    }
    __syncthreads();
    // ---- LayerNorm: one wave per row; writes fp32 + bf16 mirror
    {
        float v0 = hn[w][lane], v1 = hn[w][lane + 64];
        float s = v0 + v1;
        #pragma unroll
        for (int mask = 1; mask <= 32; mask <<= 1) s += __shfl_xor(s, mask);
        float mu = s * (1.0f/128.0f);
        float z0 = v0 - mu, z1 = v1 - mu;
        float vv = fmaf(z0, z0, z1*z1);
        #pragma unroll
        for (int mask = 1; mask <= 32; mask <<= 1) vv += __shfl_xor(vv, mask);
        float rstd = rsqrtf(vv * (1.0f/128.0f) + 1e-5f);
        float o0 = fmaf(z0 * rstd, gam[lane],      bet[lane]);
        float o1 = fmaf(z1 * rstd, gam[lane + 64], bet[lane + 64]);
        hout[(size_t)r*HID + lane]      = o0;
        hout[(size_t)r*HID + lane + 64] = o1;
        bout[(size_t)r*HID + lane]      = f2b(o0);
        bout[(size_t)r*HID + lane + 64] = f2b(o1);
    }
}

extern "C" void kernel_launch(void* const* d_in, const int* in_sizes, int n_in,
                              void* d_out, int out_size, void* d_ws, size_t ws_size,
                              hipStream_t stream)
{
    const float* x    = (const float*)d_in[0];
    const float* adj  = (const float*)d_in[1];
    const float* dist = (const float*)d_in[2];
    const float* Win  = (const float*)d_in[3];
    const float* bin  = (const float*)d_in[4];
    const float* Wu1  = (const float*)d_in[7];
    const float* bu1  = (const float*)d_in[8];
    const float* Wu2  = (const float*)d_in[9];
    const float* bu2  = (const float*)d_in[10];
    const float* gam  = (const float*)d_in[11];
    const float* bet  = (const float*)d_in[12];

    const size_t ebytes = (size_t)NN * KE * sizeof(float4);        // 10.49 MB
    const size_t lbytes = (size_t)NN * KE * sizeof(int2);          //  5.24 MB
    const size_t cbytes = ((size_t)NN * sizeof(int) + 255) & ~255; // 16 KB
    const size_t hb32   = (size_t)NN * HID * sizeof(float);        // 2 MB
    const size_t hb16   = (size_t)NN * HID * sizeof(u16);          // 1 MB

    char* p = (char*)d_ws;
    float4* edges = (float4*)p;            p += ebytes;
    int2*   cols  = (int2*)p;              p += lbytes;
    int*    nnzp  = (int*)p;               p += cbytes;
    float*  hA    = (float*)p;             p += hb32;
    u16*    bA    = (u16*)p;               p += hb16;
    u16*    bB    = (u16*)p;               p += hb16;
    float*  hB    = (float*)d_out;         // ping-pong partner; final lands here

    k_compact<<<NN/RPB, 256, 0, stream>>>(adj, cols, nnzp);
    k_weight<<<NN*KE/256, 256, 0, stream>>>(cols, nnzp, dist, edges);
    k_h0<<<NN, 128, 0, stream>>>(x, Win, bin, hA, bA);
    k_fstep<<<NN/RPB, 256, 0, stream>>>(edges, nnzp, hA, bA, Wu1, bu1, Wu2, bu2, gam, bet, hB, bB);
    k_fstep<<<NN/RPB, 256, 0, stream>>>(edges, nnzp, hB, bB, Wu1, bu1, Wu2, bu2, gam, bet, hA, bA);
    k_fstep<<<NN/RPB, 256, 0, stream>>>(edges, nnzp, hA, bA, Wu1, bu1, Wu2, bu2, gam, bet, hB, bB);
}

// Round 14
// 264.804 us; speedup vs baseline: 1.0264x; 1.0264x over previous
//
#include <hip/hip_runtime.h>
#include <hip/hip_bf16.h>

#define NN   4096
#define HID  128
#define INFE 64
#define KE   160   // edge slots/row: Binomial(4096,0.02) max ~122 across 4096 rows
#define RPB  4

typedef unsigned short u16;
typedef unsigned int   u32;

__device__ __forceinline__ float bflo(u32 w){ return __uint_as_float(w << 16); }
__device__ __forceinline__ float bfhi(u32 w){ return __uint_as_float(w & 0xffff0000u); }
__device__ __forceinline__ u16 f2b(float f) { __hip_bfloat16 h = __float2bfloat16(f); return *(u16*)&h; }

// ---- h0 = x @ W_in + b_in ; writes fp32 h and bf16 mirror ----
__global__ __launch_bounds__(128) void k_h0(
    const float* __restrict__ x, const float* __restrict__ Win, const float* __restrict__ bin,
    float* __restrict__ hdst, u16* __restrict__ bdst)
{
    __shared__ float xl[INFE];
    const int r = blockIdx.x;
    const int d = threadIdx.x;
    if (d < INFE) xl[d] = x[(size_t)r*INFE + d];
    __syncthreads();
    float acc = bin[d];
    #pragma unroll 8
    for (int k = 0; k < INFE; ++k)
        acc = fmaf(xl[k], Win[k*HID + d], acc);
    hdst[(size_t)r*HID + d] = acc;
    bdst[(size_t)r*HID + d] = f2b(acc);
}

// ---- one-shot edge build (R8/R11-proven): 2 rows/block, LDS compact, pad to x16 ----
__global__ __launch_bounds__(256) void k_build(
    const float* __restrict__ adj, const float* __restrict__ dist,
    float4* __restrict__ edges, int* __restrict__ nnzp)
{
    __shared__ int cnt[2];
    __shared__ int   cl[2][KE];
    __shared__ float ca[2][KE];
    const int r0 = blockIdx.x * 2;
    const int t  = threadIdx.x;
    if (t < 2) cnt[t] = 0;
    __syncthreads();
    float4 av[2][4];
    #pragma unroll
    for (int rr = 0; rr < 2; ++rr) {
        const float4* arow = (const float4*)(adj + (size_t)(r0+rr)*NN);
        #pragma unroll
        for (int q = 0; q < 4; ++q) av[rr][q] = arow[t + 256*q];   // 8 outstanding loads
    }
    #pragma unroll
    for (int rr = 0; rr < 2; ++rr) {
        #pragma unroll
        for (int q = 0; q < 4; ++q) {
            float a4[4] = {av[rr][q].x, av[rr][q].y, av[rr][q].z, av[rr][q].w};
            if (a4[0] != 0.f || a4[1] != 0.f || a4[2] != 0.f || a4[3] != 0.f) {
                #pragma unroll
                for (int u = 0; u < 4; ++u) {
                    if (a4[u] != 0.f) {
                        int pos = atomicAdd(&cnt[rr], 1);
                        if (pos < KE) { cl[rr][pos] = 4*(t + 256*q) + u; ca[rr][pos] = a4[u]; }
                    }
                }
            }
        }
    }
    __syncthreads();
    #pragma unroll
    for (int rr = 0; rr < 2; ++rr) {
        const int n  = cnt[rr] < KE ? cnt[rr] : KE;
        const int np = (n + 15) / 16 * 16;                 // pad to x16 with null edges
        float4* erow = edges + (size_t)(r0+rr)*KE;
        for (int i = n + t; i < np; i += 256)
            erow[i] = make_float4(__int_as_float(0), 0.f, 0.f, 0.f);
        // independent dist loads across threads -> full memory-level parallelism
        const float* drow = dist + (size_t)(r0+rr)*NN;
        for (int i = t; i < n; i += 256) {
            int   c = cl[rr][i];
            float a = ca[rr][i];
            float d  = fmaxf(drow[c], 1e-6f);
            float dw1 = a * __expf(-d * (1.0f/3.0f));
            float tt = 3.5f / d, t2 = tt*tt, t6 = t2*t2*t2;
            float dw2 = a * 0.04f * (t6*t6 - t6);          // 0.1 * 4*eps*(sr12-sr6)
            erow[i] = make_float4(__int_as_float(c), dw1, dw2, 0.f);
        }
        if (t == 0) nnzp[r0+rr] = np;
    }
}

// ---- fused step: 4 rows/block, wave=row, bf16 gathers, 16 edges/iter ----
__global__ __launch_bounds__(256) void k_fstep(
    const float4* __restrict__ edges, const int* __restrict__ nnzp,
    const float* __restrict__ h, const u16* __restrict__ hb,
    const float* __restrict__ Wu1, const float* __restrict__ bu1,
    const float* __restrict__ Wu2, const float* __restrict__ bu2,
    const float* __restrict__ gam, const float* __restrict__ bet,
    float* __restrict__ hout, u16* __restrict__ bout)
{
    __shared__ __align__(16) float4 eds[RPB][KE];   // 10 KB staged edge lists
    __shared__ int npl[RPB];
    __shared__ __align__(16) float hs[RPB][HID];
    __shared__ __align__(16) float ms[RPB][HID];
    __shared__ __align__(16) float h1s[RPB][HID];
    __shared__ float hn[RPB][HID];
    const int t    = threadIdx.x;
    const int w    = t >> 6;        // wave id = local row
    const int lane = t & 63;
    const int g    = lane >> 5;     // 32-lane half: edge parity
    const int j    = lane & 31;     // owns dims 4j..4j+3
    const int r0   = blockIdx.x * RPB;
    const int r    = r0 + w;

    if (t < RPB) npl[t] = nnzp[r0 + t];
    const float4 hi4 = *(const float4*)(h + (size_t)r*HID + 4*j);
    if (g == 0) *(float4*)&hs[w][4*j] = hi4;
    __syncthreads();
    #pragma unroll
    for (int rr = 0; rr < RPB; ++rr) {
        const float4* er = edges + (size_t)(r0+rr)*KE;
        for (int i = t; i < npl[rr]; i += 256) eds[rr][i] = er[i];
    }
    __syncthreads();

    // ---- message phase: 16 edges/iter, 8 in flight per 32-lane half ----
    const int np = npl[w];
    float4 macc = make_float4(0.f, 0.f, 0.f, 0.f);
    for (int e0 = 0; e0 < np; e0 += 16) {
        float4 ed[8]; uint2 hj16[8]; float p[8];
        #pragma unroll
        for (int q = 0; q < 8; ++q) ed[q] = eds[w][e0 + g + 2*q];
        #pragma unroll
        for (int q = 0; q < 8; ++q) {
            int c = __float_as_int(ed[q].x);
            hj16[q] = *(const uint2*)(hb + (size_t)c*HID + 4*j);   // 8 outstanding 8B gathers
        }
        float4 hjf[8];
        #pragma unroll
        for (int q = 0; q < 8; ++q) {
            hjf[q].x = bflo(hj16[q].x); hjf[q].y = bfhi(hj16[q].x);
            hjf[q].z = bflo(hj16[q].y); hjf[q].w = bfhi(hj16[q].y);
            p[q] = hi4.x*hjf[q].x;
            p[q] = fmaf(hi4.y, hjf[q].y, p[q]);
            p[q] = fmaf(hi4.z, hjf[q].z, p[q]);
            p[q] = fmaf(hi4.w, hjf[q].w, p[q]);
        }
        #pragma unroll
        for (int mask = 1; mask <= 16; mask <<= 1) {   // 8 independent chains
            #pragma unroll
            for (int q = 0; q < 8; ++q) p[q] += __shfl_xor(p[q], mask);
        }
        #pragma unroll
        for (int q = 0; q < 8; ++q) {
            float wq = fmaf(ed[q].y, fmaxf(p[q], 0.f), ed[q].z);
            macc.x = fmaf(wq, hjf[q].x, macc.x);
            macc.y = fmaf(wq, hjf[q].y, macc.y);
            macc.z = fmaf(wq, hjf[q].z, macc.z);
            macc.w = fmaf(wq, hjf[q].w, macc.w);
        }
    }
    macc.x += __shfl_xor(macc.x, 32);   // combine the two halves' edge subsets
    macc.y += __shfl_xor(macc.y, 32);
    macc.z += __shfl_xor(macc.z, 32);
    macc.w += __shfl_xor(macc.w, 32);
    if (g == 0) *(float4*)&ms[w][4*j] = macc;
    __syncthreads();

    // ---- MLP phase A: h1 = relu([h,m] @ Wu1 + b1); weights shared across 2 rows
    {
        const int half = t >> 7;
        const int d    = t & 127;
        const int ra = 2*half, rb = ra + 1;
        float bb = bu1[d];
        float a0 = bb, a1 = bb;
        for (int k = 0; k < HID; k += 4) {
            float w0 = Wu1[(k+0)*HID + d], w1 = Wu1[(k+1)*HID + d];
            float w2 = Wu1[(k+2)*HID + d], w3 = Wu1[(k+3)*HID + d];
            float4 caa = *(const float4*)&hs[ra][k];
            float4 cbb = *(const float4*)&hs[rb][k];
            a0 = fmaf(caa.x,w0,a0); a0 = fmaf(caa.y,w1,a0); a0 = fmaf(caa.z,w2,a0); a0 = fmaf(caa.w,w3,a0);
            a1 = fmaf(cbb.x,w0,a1); a1 = fmaf(cbb.y,w1,a1); a1 = fmaf(cbb.z,w2,a1); a1 = fmaf(cbb.w,w3,a1);
        }
        for (int k = 0; k < HID; k += 4) {
            float w0 = Wu1[(HID+k+0)*HID + d], w1 = Wu1[(HID+k+1)*HID + d];
            float w2 = Wu1[(HID+k+2)*HID + d], w3 = Wu1[(HID+k+3)*HID + d];
            float4 caa = *(const float4*)&ms[ra][k];
            float4 cbb = *(const float4*)&ms[rb][k];
            a0 = fmaf(caa.x,w0,a0); a0 = fmaf(caa.y,w1,a0); a0 = fmaf(caa.z,w2,a0); a0 = fmaf(caa.w,w3,a0);
            a1 = fmaf(cbb.x,w0,a1); a1 = fmaf(cbb.y,w1,a1); a1 = fmaf(cbb.z,w2,a1); a1 = fmaf(cbb.w,w3,a1);
        }
        h1s[ra][d] = fmaxf(a0, 0.f);
        h1s[rb][d] = fmaxf(a1, 0.f);
    }
    __syncthreads();
    // ---- MLP phase B: hn = h + (h1 @ Wu2 + b2)
    {
        const int half = t >> 7;
        const int d    = t & 127;
        const int ra = 2*half, rb = ra + 1;
        float bb = bu2[d];
        float b0 = bb, b1 = bb;
        for (int k = 0; k < HID; k += 4) {
            float w0 = Wu2[(k+0)*HID + d], w1 = Wu2[(k+1)*HID + d];
            float w2 = Wu2[(k+2)*HID + d], w3 = Wu2[(k+3)*HID + d];
            float4 caa = *(const float4*)&h1s[ra][k];
            float4 cbb = *(const float4*)&h1s[rb][k];
            b0 = fmaf(caa.x,w0,b0); b0 = fmaf(caa.y,w1,b0); b0 = fmaf(caa.z,w2,b0); b0 = fmaf(caa.w,w3,b0);
            b1 = fmaf(cbb.x,w0,b1); b1 = fmaf(cbb.y,w1,b1); b1 = fmaf(cbb.z,w2,b1); b1 = fmaf(cbb.w,w3,b1);
        }
        hn[ra][d] = hs[ra][d] + b0;
        hn[rb][d] = hs[rb][d] + b1;
    }
    __syncthreads();
    // ---- LayerNorm: one wave per row; writes fp32 + bf16 mirror
    {
        float v0 = hn[w][lane], v1 = hn[w][lane + 64];
        float s = v0 + v1;
        #pragma unroll
        for (int mask = 1; mask <= 32; mask <<= 1) s += __shfl_xor(s, mask);
        float mu = s * (1.0f/128.0f);
        float z0 = v0 - mu, z1 = v1 - mu;
        float vv = fmaf(z0, z0, z1*z1);
        #pragma unroll
        for (int mask = 1; mask <= 32; mask <<= 1) vv += __shfl_xor(vv, mask);
        float rstd = rsqrtf(vv * (1.0f/128.0f) + 1e-5f);
        float o0 = fmaf(z0 * rstd, gam[lane],      bet[lane]);
        float o1 = fmaf(z1 * rstd, gam[lane + 64], bet[lane + 64]);
        hout[(size_t)r*HID + lane]      = o0;
        hout[(size_t)r*HID + lane + 64] = o1;
        bout[(size_t)r*HID + lane]      = f2b(o0);
        bout[(size_t)r*HID + lane + 64] = f2b(o1);
    }
}

extern "C" void kernel_launch(void* const* d_in, const int* in_sizes, int n_in,
                              void* d_out, int out_size, void* d_ws, size_t ws_size,
                              hipStream_t stream)
{
    const float* x    = (const float*)d_in[0];
    const float* adj  = (const float*)d_in[1];
    const float* dist = (const float*)d_in[2];
    const float* Win  = (const float*)d_in[3];
    const float* bin  = (const float*)d_in[4];
    const float* Wu1  = (const float*)d_in[7];
    const float* bu1  = (const float*)d_in[8];
    const float* Wu2  = (const float*)d_in[9];
    const float* bu2  = (const float*)d_in[10];
    const float* gam  = (const float*)d_in[11];
    const float* bet  = (const float*)d_in[12];

    const size_t ebytes = (size_t)NN * KE * sizeof(float4);        // 10.49 MB
    const size_t cbytes = ((size_t)NN * sizeof(int) + 255) & ~255; // 16 KB
    const size_t hb32   = (size_t)NN * HID * sizeof(float);        // 2 MB
    const size_t hb16   = (size_t)NN * HID * sizeof(u16);          // 1 MB

    char* p = (char*)d_ws;
    float4* edges = (float4*)p;            p += ebytes;
    int*    nnzp  = (int*)p;               p += cbytes;
    float*  hA    = (float*)p;             p += hb32;
    u16*    bA    = (u16*)p;               p += hb16;
    u16*    bB    = (u16*)p;               p += hb16;
    float*  hB    = (float*)d_out;         // ping-pong partner; final lands here

    k_build<<<NN/2, 256, 0, stream>>>(adj, dist, edges, nnzp);
    k_h0<<<NN, 128, 0, stream>>>(x, Win, bin, hA, bA);
    k_fstep<<<NN/RPB, 256, 0, stream>>>(edges, nnzp, hA, bA, Wu1, bu1, Wu2, bu2, gam, bet, hB, bB);
    k_fstep<<<NN/RPB, 256, 0, stream>>>(edges, nnzp, hB, bB, Wu1, bu1, Wu2, bu2, gam, bet, hA, bA);
    k_fstep<<<NN/RPB, 256, 0, stream>>>(edges, nnzp, hA, bA, Wu1, bu1, Wu2, bu2, gam, bet, hB, bB);
}